// Round 6
// baseline (450.832 us; speedup 1.0000x reference)
//
#include <hip/hip_runtime.h>
#include <hip/hip_bf16.h>

typedef __bf16 bf16x8 __attribute__((ext_vector_type(8)));
typedef float f32x4 __attribute__((ext_vector_type(4)));

using bf = __hip_bfloat16;

constexpr int cB = 16, cH = 96, cW = 96, cC = 192;
constexpr int cT = cH * cW;       // 9216
constexpr int cM = cB * cT;       // 147456
constexpr int CH = 96;            // wkv chunk length
constexpr int NS = cT / CH;       // 96 chunks
constexpr float Tinv = 1.0f / 9216.0f;
constexpr int NTILE = cM / 64;    // 2304 m-tiles of 64 rows

__device__ __forceinline__ int swz(int row, int bytecol) {
    return row * 384 + (bytecol ^ ((row & 7) << 4));
}
__device__ __forceinline__ unsigned bfbits(float x) {
    bf h = __float2bfloat16(x);
    return (unsigned)*reinterpret_cast<unsigned short*>(&h);
}

// ---------------------------------------------------------------------------
// Pre-convert weights f32 -> bf16, concatenated rows: [Wk;Wv;Wr;Wo] (768x192)
// ---------------------------------------------------------------------------
__global__ __launch_bounds__(256) void convw_k(
    const float* __restrict__ Wk, const float* __restrict__ Wv,
    const float* __restrict__ Wr, const float* __restrict__ Wo,
    bf* __restrict__ out)
{
    int i = (blockIdx.x * 256 + threadIdx.x) * 8;
    int mat = i / 36864, off = i % 36864;
    const float* s = mat == 0 ? Wk : (mat == 1 ? Wv : (mat == 2 ? Wr : Wo));
    const float4* sp = reinterpret_cast<const float4*>(s + off);
    float4 a0 = sp[0], a1 = sp[1];
    bf16x8 pk;
    pk[0]=(__bf16)a0.x; pk[1]=(__bf16)a0.y; pk[2]=(__bf16)a0.z; pk[3]=(__bf16)a0.w;
    pk[4]=(__bf16)a1.x; pk[5]=(__bf16)a1.y; pk[6]=(__bf16)a1.z; pk[7]=(__bf16)a1.w;
    *reinterpret_cast<bf16x8*>(reinterpret_cast<__bf16*>(out) + i) = pk;
}

// ---------------------------------------------------------------------------
// Persistent pipelined GEMM. 256 blocks (1/CU), 512 threads (8 waves, 2m x 4n).
// LDS: A double-buffer 2x(64x384B)=48KB + full B matrix (192x384B)=72KB.
// Per m-step: issue A-loads(t+1) | compute(t) | store(t) | ds_write(t+1) | bar.
// MODE 0: A = x(f32)+2D shift; 3 mats -> kT/vT/sigmoid(r)T  TRANSPOSED [c][m].
// MODE 1: A = z(bf16) [m][c]; 1 mat (Wo) -> out f32 [m][c].
// ---------------------------------------------------------------------------
template <int MODE>
__global__ __launch_bounds__(512, 2) void gemm_k(
    const void* __restrict__ Ap, const bf* __restrict__ Wb,
    void* __restrict__ O0, void* __restrict__ O1, void* __restrict__ O2)
{
    constexpr int NMAT = (MODE == 0) ? 3 : 1;
    __shared__ char lds[2 * 64 * 384 + 192 * 384];
    const int tid = threadIdx.x, bx = blockIdx.x;
    const int lane = tid & 63, wid = tid >> 6;
    const int wm = wid >> 2, wn = wid & 3;   // 2m x 4n waves: 32 x 48 each
    const int lr = lane & 15, lq = lane >> 4;

    // per-thread staging coords (3 chunks of 8 elems, fixed per thread)
    int rj[3], kbj[3];
#pragma unroll
    for (int j = 0; j < 3; ++j) { int idx = tid + j * 512; rj[j] = idx / 24; kbj[j] = idx % 24; }

    float4 pf[6];    // MODE0: 3 chunks x 2 float4
    int4   pi[3];    // MODE1: 3 chunks x int4

    for (int mat = 0; mat < NMAT; ++mat) {
        // ---- stage B: full 192x192 bf16 matrix, swizzled ----
        {
            const bf* Wt = Wb + (size_t)mat * 192 * cC;
            char* Bb = &lds[0] + 2 * 64 * 384;
            for (int it = 0; it < 9; ++it) {
                int idx = tid + it * 512;
                int r = idx / 24, kb = idx % 24;
                int4 val = *reinterpret_cast<const int4*>(Wt + r * cC + kb * 8);
                *reinterpret_cast<int4*>(Bb + swz(r, kb * 16)) = val;
            }
        }
        // ---- prologue: load + write A(tile bx) into buf0 ----
        if constexpr (MODE == 0) {
            const float* Af = (const float*)Ap;
#pragma unroll
            for (int j = 0; j < 3; ++j) {
                int gm = bx * 64 + rj[j];
                int b = gm / cT, t = gm % cT, h = t / cW, w = t % cW;
                int grp = kbj[j] / 6;
                int hs = h + (grp == 2 ? -1 : (grp == 3 ? 1 : 0));
                int ws2 = w + (grp == 0 ? -1 : (grp == 1 ? 1 : 0));
                pf[2*j] = float4{0,0,0,0}; pf[2*j+1] = float4{0,0,0,0};
                if (hs >= 0 && hs < cH && ws2 >= 0 && ws2 < cW) {
                    const float4* s = reinterpret_cast<const float4*>(
                        Af + ((size_t)b * cT + (size_t)hs * cW + ws2) * cC + kbj[j] * 8);
                    pf[2*j] = s[0]; pf[2*j+1] = s[1];
                }
            }
#pragma unroll
            for (int j = 0; j < 3; ++j) {
                bf16x8 pk;
                pk[0]=(__bf16)pf[2*j].x; pk[1]=(__bf16)pf[2*j].y; pk[2]=(__bf16)pf[2*j].z; pk[3]=(__bf16)pf[2*j].w;
                pk[4]=(__bf16)pf[2*j+1].x; pk[5]=(__bf16)pf[2*j+1].y; pk[6]=(__bf16)pf[2*j+1].z; pk[7]=(__bf16)pf[2*j+1].w;
                *reinterpret_cast<bf16x8*>(&lds[0] + swz(rj[j], kbj[j] * 16)) = pk;
            }
        } else {
            const bf* Az = (const bf*)Ap;
#pragma unroll
            for (int j = 0; j < 3; ++j)
                pi[j] = *reinterpret_cast<const int4*>(Az + (size_t)(bx * 64 + rj[j]) * cC + kbj[j] * 8);
#pragma unroll
            for (int j = 0; j < 3; ++j)
                *reinterpret_cast<int4*>(&lds[0] + swz(rj[j], kbj[j] * 16)) = pi[j];
        }
        __syncthreads();

        for (int i = 0; i < 9; ++i) {
            const int tix = bx + 256 * i;
            // ---- issue A-loads for next tile (overlap with compute) ----
            if (i < 8) {
                const int tn = bx + 256 * (i + 1);
                if constexpr (MODE == 0) {
                    const float* Af = (const float*)Ap;
#pragma unroll
                    for (int j = 0; j < 3; ++j) {
                        int gm = tn * 64 + rj[j];
                        int b = gm / cT, t = gm % cT, h = t / cW, w = t % cW;
                        int grp = kbj[j] / 6;
                        int hs = h + (grp == 2 ? -1 : (grp == 3 ? 1 : 0));
                        int ws2 = w + (grp == 0 ? -1 : (grp == 1 ? 1 : 0));
                        pf[2*j] = float4{0,0,0,0}; pf[2*j+1] = float4{0,0,0,0};
                        if (hs >= 0 && hs < cH && ws2 >= 0 && ws2 < cW) {
                            const float4* s = reinterpret_cast<const float4*>(
                                Af + ((size_t)b * cT + (size_t)hs * cW + ws2) * cC + kbj[j] * 8);
                            pf[2*j] = s[0]; pf[2*j+1] = s[1];
                        }
                    }
                } else {
                    const bf* Az = (const bf*)Ap;
#pragma unroll
                    for (int j = 0; j < 3; ++j)
                        pi[j] = *reinterpret_cast<const int4*>(Az + (size_t)(tn * 64 + rj[j]) * cC + kbj[j] * 8);
                }
            }
            // ---- compute from buf[i&1] + full-B LDS ----
            char* Ab = &lds[0] + (i & 1) * (64 * 384);
            char* Bb = &lds[0] + 2 * 64 * 384;
            f32x4 acc[2][3] = {};
#pragma unroll
            for (int kk = 0; kk < 6; ++kk) {
                const int bc = kk * 64 + lq * 16;
                bf16x8 af[2], bfr[3];
#pragma unroll
                for (int mt = 0; mt < 2; ++mt)
                    af[mt] = *reinterpret_cast<const bf16x8*>(Ab + swz(wm * 32 + mt * 16 + lr, bc));
#pragma unroll
                for (int nt = 0; nt < 3; ++nt)
                    bfr[nt] = *reinterpret_cast<const bf16x8*>(Bb + swz(wn * 48 + nt * 16 + lr, bc));
#pragma unroll
                for (int mt = 0; mt < 2; ++mt)
#pragma unroll
                    for (int nt = 0; nt < 3; ++nt)
                        acc[mt][nt] = __builtin_amdgcn_mfma_f32_16x16x32_bf16(
                            af[mt], bfr[nt], acc[mt][nt], 0, 0, 0);
            }
            // ---- store tile tix ----
            if constexpr (MODE == 0) {
                bf* OT = (bf*)(mat == 0 ? O0 : (mat == 1 ? O1 : O2));
#pragma unroll
                for (int mt = 0; mt < 2; ++mt)
#pragma unroll
                    for (int nt = 0; nt < 3; ++nt) {
                        int c = wn * 48 + nt * 16 + lr;
                        int m = tix * 64 + wm * 32 + mt * 16 + lq * 4;
                        f32x4 a = acc[mt][nt];
                        if (mat == 2) {
#pragma unroll
                            for (int j = 0; j < 4; ++j) a[j] = 1.0f / (1.0f + __expf(-a[j]));
                        }
                        uint2 d;
                        d.x = bfbits(a[0]) | (bfbits(a[1]) << 16);
                        d.y = bfbits(a[2]) | (bfbits(a[3]) << 16);
                        *reinterpret_cast<uint2*>(OT + (size_t)c * cM + m) = d;
                    }
            } else {
                float* Os = (float*)O0;
#pragma unroll
                for (int mt = 0; mt < 2; ++mt)
#pragma unroll
                    for (int nt = 0; nt < 3; ++nt)
#pragma unroll
                        for (int j = 0; j < 4; ++j) {
                            int row = tix * 64 + wm * 32 + mt * 16 + lq * 4 + j;
                            int col = wn * 48 + nt * 16 + lr;
                            Os[(size_t)row * cC + col] = acc[mt][nt][j];
                        }
            }
            // ---- write next A tile into the other buffer ----
            if (i < 8) {
                char* An = &lds[0] + ((i + 1) & 1) * (64 * 384);
                if constexpr (MODE == 0) {
#pragma unroll
                    for (int j = 0; j < 3; ++j) {
                        bf16x8 pk;
                        pk[0]=(__bf16)pf[2*j].x; pk[1]=(__bf16)pf[2*j].y; pk[2]=(__bf16)pf[2*j].z; pk[3]=(__bf16)pf[2*j].w;
                        pk[4]=(__bf16)pf[2*j+1].x; pk[5]=(__bf16)pf[2*j+1].y; pk[6]=(__bf16)pf[2*j+1].z; pk[7]=(__bf16)pf[2*j+1].w;
                        *reinterpret_cast<bf16x8*>(An + swz(rj[j], kbj[j] * 16)) = pk;
                    }
                } else {
#pragma unroll
                    for (int j = 0; j < 3; ++j)
                        *reinterpret_cast<int4*>(An + swz(rj[j], kbj[j] * 16)) = pi[j];
                }
            }
            __syncthreads();
        }
    }
}

// ---------------------------------------------------------------------------
// WKV over TRANSPOSED k/v/sr [c][b*T+t]: fully coalesced per-channel t-runs.
// State (p,q,o): true numerator = p*e^o, denom = q*e^o.
// ---------------------------------------------------------------------------
__global__ __launch_bounds__(192) void wkv_pass1(
    const bf* __restrict__ kT, const bf* __restrict__ vT,
    const float* __restrict__ sd,
    float* __restrict__ stP, float* __restrict__ stQ, float* __restrict__ stO)
{
    const int c = threadIdx.x, b = blockIdx.y, ch = blockIdx.x;
    const float w = sd[c] * Tinv;
    size_t base = (size_t)c * cM + (size_t)b * cT + ch * CH;
    float p = 0.f, q = 0.f, o = -1e38f;
    for (int g = 0; g < 12; ++g) {
        bf16x8 k8 = *reinterpret_cast<const bf16x8*>(kT + base + g * 8);
        bf16x8 v8 = *reinterpret_cast<const bf16x8*>(vT + base + g * 8);
#pragma unroll
        for (int j = 0; j < 8; ++j) {
            float kt = (float)k8[j], vt = (float)v8[j];
            float no = fmaxf(w + o, kt);
            float A2 = __expf(w + o - no), B2 = __expf(kt - no);
            p = A2 * p + B2 * vt; q = A2 * q + B2; o = no;
        }
    }
    size_t si = ((size_t)b * NS + ch) * cC + c;
    stP[si] = p; stQ[si] = q; stO[si] = o;
}

__global__ __launch_bounds__(192) void wkv_pass2(
    const float* __restrict__ stP, const float* __restrict__ stQ,
    const float* __restrict__ stO, const float* __restrict__ sd,
    float* __restrict__ iP, float* __restrict__ iQ, float* __restrict__ iO)
{
    const int c = threadIdx.x, b = blockIdx.x;
    const float w = sd[c] * Tinv;
    const float Lw = w * (float)CH;
    float p = 0.f, q = 0.f, o = -1e38f;
    size_t si = (size_t)b * NS * cC + c;
    float sp = stP[si], sq = stQ[si], so = stO[si];
    for (int ch = 0; ch < NS; ++ch) {
        float np_ = 0.f, nq_ = 0.f, no_ = -1e38f;
        if (ch + 1 < NS) {
            size_t sj = si + (size_t)(ch + 1) * cC;
            np_ = stP[sj]; nq_ = stQ[sj]; no_ = stO[sj];
        }
        size_t sc = si + (size_t)ch * cC;
        iP[sc] = p; iQ[sc] = q; iO[sc] = o;   // exclusive prefix
        float po = o + Lw;
        float m = fmaxf(po, so);
        float e1 = __expf(po - m), e2 = __expf(so - m);
        p = e1 * p + e2 * sp;
        q = e1 * q + e2 * sq;
        o = m;
        sp = np_; sq = nq_; so = no_;
    }
}

// reads kT/vT/srT [c][m] coalesced; writes z [m][c] (row-coalesced across threads)
__global__ __launch_bounds__(192) void wkv_pass3(
    const bf* __restrict__ kT, const bf* __restrict__ vT, const bf* __restrict__ srT,
    const float* __restrict__ sd, const float* __restrict__ sf,
    const float* __restrict__ iP, const float* __restrict__ iQ,
    const float* __restrict__ iO, bf* __restrict__ z)
{
    const int c = threadIdx.x, b = blockIdx.y, ch = blockIdx.x;
    const float w = sd[c] * Tinv, u = sf[c] * Tinv;
    size_t si = ((size_t)b * NS + ch) * cC + c;
    float p = iP[si], q = iQ[si], o = iO[si];
    size_t base = (size_t)c * cM + (size_t)b * cT + ch * CH;
    size_t zbase = ((size_t)b * cT + (size_t)ch * CH) * cC + c;
    for (int g = 0; g < 12; ++g) {
        bf16x8 k8 = *reinterpret_cast<const bf16x8*>(kT + base + g * 8);
        bf16x8 v8 = *reinterpret_cast<const bf16x8*>(vT + base + g * 8);
        bf16x8 r8 = *reinterpret_cast<const bf16x8*>(srT + base + g * 8);
#pragma unroll
        for (int j = 0; j < 8; ++j) {
            float kt = (float)k8[j], vt = (float)v8[j], rt = (float)r8[j];
            float no = fmaxf(o, u + kt);
            float Ae = __expf(o - no), Be = __expf(u + kt - no);
            float y = (Ae * p + Be * vt) / (Ae * q + Be);
            z[zbase + (size_t)(g * 8 + j) * cC] = __float2bfloat16(rt * y);
            float no2 = fmaxf(w + o, kt);
            float A2 = __expf(w + o - no2), B2 = __expf(kt - no2);
            p = A2 * p + B2 * vt; q = A2 * q + B2; o = no2;
        }
    }
}

extern "C" void kernel_launch(void* const* d_in, const int* in_sizes, int n_in,
                              void* d_out, int out_size, void* d_ws, size_t ws_size,
                              hipStream_t stream)
{
    const float* x  = (const float*)d_in[0];
    const float* Wk = (const float*)d_in[1];
    const float* Wv = (const float*)d_in[2];
    const float* Wr = (const float*)d_in[3];
    const float* Wo = (const float*)d_in[4];
    const float* sd = (const float*)d_in[5];
    const float* sf = (const float*)d_in[6];
    float* out = (float*)d_out;

    const size_t nEl = (size_t)cM * cC;          // 28,311,552 elements
    // d_out (f32, 113.2MB) holds kT and srT (bf16, 2x56.6MB) until gemm1.
    bf* kT  = (bf*)d_out;
    bf* srT = (bf*)d_out + nEl;
    char* ws = (char*)d_ws;
    bf* vT = (bf*)ws;                             // 56.6MB
    bf* z  = (bf*)(ws + 2 * nEl);                 // 56.6MB, [m][c]
    const size_t stN = (size_t)cB * NS * cC;      // 294,912 floats each
    float* stP = (float*)(ws + 4 * nEl);
    float* stQ = stP + stN;
    float* stO = stQ + stN;
    float* iP  = stO + stN;
    float* iQ  = iP + stN;
    float* iO  = iQ + stN;
    bf* wbf = (bf*)(iO + stN);                    // [Wk;Wv;Wr;Wo] bf16, 768x192

    convw_k<<<dim3(72), dim3(256), 0, stream>>>(Wk, Wv, Wr, Wo, wbf);
    gemm_k<0><<<dim3(256), dim3(512), 0, stream>>>(x, wbf, kT, vT, srT);
    wkv_pass1<<<dim3(NS, cB), dim3(192), 0, stream>>>(kT, vT, sd, stP, stQ, stO);
    wkv_pass2<<<dim3(cB), dim3(192), 0, stream>>>(stP, stQ, stO, sd, iP, iQ, iO);
    wkv_pass3<<<dim3(NS, cB), dim3(192), 0, stream>>>(
        kT, vT, srT, sd, sf, iP, iQ, iO, z);
    gemm_k<1><<<dim3(256), dim3(512), 0, stream>>>(
        z, wbf + (size_t)576 * cC, out, nullptr, nullptr);
}

// Round 7
// 245.083 us; speedup vs baseline: 1.8395x; 1.8395x over previous
//
#include <hip/hip_runtime.h>
#include <hip/hip_bf16.h>

typedef __bf16 bf16x8 __attribute__((ext_vector_type(8)));
typedef float f32x4 __attribute__((ext_vector_type(4)));

using bf = __hip_bfloat16;

constexpr int cB = 16, cH = 96, cW = 96, cC = 192;
constexpr int cT = cH * cW;       // 9216
constexpr int cM = cB * cT;       // 147456
constexpr int CH = 96;            // wkv chunk length
constexpr int NS = cT / CH;       // 96 chunks
constexpr float Tinv = 1.0f / 9216.0f;

__device__ __forceinline__ int swz(int row, int bytecol) {
    return row * 384 + (bytecol ^ ((row & 7) << 4));
}
__device__ __forceinline__ float bflo(unsigned u) { return __uint_as_float(u << 16); }
__device__ __forceinline__ float bfhi(unsigned u) { return __uint_as_float(u & 0xffff0000u); }

// ---------------------------------------------------------------------------
// Pre-convert weights f32 -> bf16, concatenated rows: [Wk;Wv;Wr;Wo] (768x192)
// ---------------------------------------------------------------------------
__global__ __launch_bounds__(256) void convw_k(
    const float* __restrict__ Wk, const float* __restrict__ Wv,
    const float* __restrict__ Wr, const float* __restrict__ Wo,
    bf* __restrict__ out)
{
    int i = (blockIdx.x * 256 + threadIdx.x) * 8;
    int mat = i / 36864, off = i % 36864;
    const float* s = mat == 0 ? Wk : (mat == 1 ? Wv : (mat == 2 ? Wr : Wo));
    const float4* sp = reinterpret_cast<const float4*>(s + off);
    float4 a0 = sp[0], a1 = sp[1];
    bf16x8 pk;
    pk[0]=(__bf16)a0.x; pk[1]=(__bf16)a0.y; pk[2]=(__bf16)a0.z; pk[3]=(__bf16)a0.w;
    pk[4]=(__bf16)a1.x; pk[5]=(__bf16)a1.y; pk[6]=(__bf16)a1.z; pk[7]=(__bf16)a1.w;
    *reinterpret_cast<bf16x8*>(reinterpret_cast<__bf16*>(out) + i) = pk;
}

// ---------------------------------------------------------------------------
// Persistent pipelined GEMM. 256 blocks (1/CU), 512 threads (8 waves, 2m x 4n).
// LDS: A double-buffer 2x(64x384B)=48KB + full B matrix (192x384B)=72KB.
// Per m-step: issue A-loads(t+1) | compute(t) | store(t) | ds_write(t+1) | bar.
// Outputs are [m][c] (WKV-friendly; 16-lane 32B store sectors coalesce fine).
// MODE 0: A = x(f32)+2D shift; 3 mats -> k / v / sigmoid(r) bf16.
// MODE 1: A = z(bf16) [m][c]; 1 mat (Wo) -> out f32 [m][c].
// ---------------------------------------------------------------------------
template <int MODE>
__global__ __launch_bounds__(512, 2) void gemm_k(
    const void* __restrict__ Ap, const bf* __restrict__ Wb,
    void* __restrict__ O0, void* __restrict__ O1, void* __restrict__ O2)
{
    constexpr int NMAT = (MODE == 0) ? 3 : 1;
    __shared__ char lds[2 * 64 * 384 + 192 * 384];
    const int tid = threadIdx.x, bx = blockIdx.x;
    const int lane = tid & 63, wid = tid >> 6;
    const int wm = wid >> 2, wn = wid & 3;   // 2m x 4n waves: 32 x 48 each
    const int lr = lane & 15, lq = lane >> 4;

    // per-thread staging coords (3 chunks of 8 elems, fixed per thread)
    int rj[3], kbj[3];
#pragma unroll
    for (int j = 0; j < 3; ++j) { int idx = tid + j * 512; rj[j] = idx / 24; kbj[j] = idx % 24; }

    float4 pf[6];    // MODE0: 3 chunks x 2 float4
    int4   pi[3];    // MODE1: 3 chunks x int4

    for (int mat = 0; mat < NMAT; ++mat) {
        // ---- stage B: full 192x192 bf16 matrix, swizzled ----
        {
            const bf* Wt = Wb + (size_t)mat * 192 * cC;
            char* Bb = &lds[0] + 2 * 64 * 384;
            for (int it = 0; it < 9; ++it) {
                int idx = tid + it * 512;
                int r = idx / 24, kb = idx % 24;
                int4 val = *reinterpret_cast<const int4*>(Wt + r * cC + kb * 8);
                *reinterpret_cast<int4*>(Bb + swz(r, kb * 16)) = val;
            }
        }
        // ---- prologue: load + write A(tile bx) into buf0 ----
        if constexpr (MODE == 0) {
            const float* Af = (const float*)Ap;
#pragma unroll
            for (int j = 0; j < 3; ++j) {
                int gm = bx * 64 + rj[j];
                int b = gm / cT, t = gm % cT, h = t / cW, w = t % cW;
                int grp = kbj[j] / 6;
                int hs = h + (grp == 2 ? -1 : (grp == 3 ? 1 : 0));
                int ws2 = w + (grp == 0 ? -1 : (grp == 1 ? 1 : 0));
                pf[2*j] = float4{0,0,0,0}; pf[2*j+1] = float4{0,0,0,0};
                if (hs >= 0 && hs < cH && ws2 >= 0 && ws2 < cW) {
                    const float4* s = reinterpret_cast<const float4*>(
                        Af + ((size_t)b * cT + (size_t)hs * cW + ws2) * cC + kbj[j] * 8);
                    pf[2*j] = s[0]; pf[2*j+1] = s[1];
                }
            }
#pragma unroll
            for (int j = 0; j < 3; ++j) {
                bf16x8 pk;
                pk[0]=(__bf16)pf[2*j].x; pk[1]=(__bf16)pf[2*j].y; pk[2]=(__bf16)pf[2*j].z; pk[3]=(__bf16)pf[2*j].w;
                pk[4]=(__bf16)pf[2*j+1].x; pk[5]=(__bf16)pf[2*j+1].y; pk[6]=(__bf16)pf[2*j+1].z; pk[7]=(__bf16)pf[2*j+1].w;
                *reinterpret_cast<bf16x8*>(&lds[0] + swz(rj[j], kbj[j] * 16)) = pk;
            }
        } else {
            const bf* Az = (const bf*)Ap;
#pragma unroll
            for (int j = 0; j < 3; ++j)
                pi[j] = *reinterpret_cast<const int4*>(Az + (size_t)(bx * 64 + rj[j]) * cC + kbj[j] * 8);
#pragma unroll
            for (int j = 0; j < 3; ++j)
                *reinterpret_cast<int4*>(&lds[0] + swz(rj[j], kbj[j] * 16)) = pi[j];
        }
        __syncthreads();

        for (int i = 0; i < 9; ++i) {
            const int tix = bx + 256 * i;
            // ---- issue A-loads for next tile (overlap with compute) ----
            if (i < 8) {
                const int tn = bx + 256 * (i + 1);
                if constexpr (MODE == 0) {
                    const float* Af = (const float*)Ap;
#pragma unroll
                    for (int j = 0; j < 3; ++j) {
                        int gm = tn * 64 + rj[j];
                        int b = gm / cT, t = gm % cT, h = t / cW, w = t % cW;
                        int grp = kbj[j] / 6;
                        int hs = h + (grp == 2 ? -1 : (grp == 3 ? 1 : 0));
                        int ws2 = w + (grp == 0 ? -1 : (grp == 1 ? 1 : 0));
                        pf[2*j] = float4{0,0,0,0}; pf[2*j+1] = float4{0,0,0,0};
                        if (hs >= 0 && hs < cH && ws2 >= 0 && ws2 < cW) {
                            const float4* s = reinterpret_cast<const float4*>(
                                Af + ((size_t)b * cT + (size_t)hs * cW + ws2) * cC + kbj[j] * 8);
                            pf[2*j] = s[0]; pf[2*j+1] = s[1];
                        }
                    }
                } else {
                    const bf* Az = (const bf*)Ap;
#pragma unroll
                    for (int j = 0; j < 3; ++j)
                        pi[j] = *reinterpret_cast<const int4*>(Az + (size_t)(tn * 64 + rj[j]) * cC + kbj[j] * 8);
                }
            }
            // ---- compute from buf[i&1] + full-B LDS ----
            char* Ab = &lds[0] + (i & 1) * (64 * 384);
            char* Bb = &lds[0] + 2 * 64 * 384;
            f32x4 acc[2][3] = {};
#pragma unroll
            for (int kk = 0; kk < 6; ++kk) {
                const int bc = kk * 64 + lq * 16;
                bf16x8 af[2], bfr[3];
#pragma unroll
                for (int mt = 0; mt < 2; ++mt)
                    af[mt] = *reinterpret_cast<const bf16x8*>(Ab + swz(wm * 32 + mt * 16 + lr, bc));
#pragma unroll
                for (int nt = 0; nt < 3; ++nt)
                    bfr[nt] = *reinterpret_cast<const bf16x8*>(Bb + swz(wn * 48 + nt * 16 + lr, bc));
#pragma unroll
                for (int mt = 0; mt < 2; ++mt)
#pragma unroll
                    for (int nt = 0; nt < 3; ++nt)
                        acc[mt][nt] = __builtin_amdgcn_mfma_f32_16x16x32_bf16(
                            af[mt], bfr[nt], acc[mt][nt], 0, 0, 0);
            }
            // ---- store tile tix, [m][c] layout ----
            if constexpr (MODE == 0) {
                bf* Os = (bf*)(mat == 0 ? O0 : (mat == 1 ? O1 : O2));
#pragma unroll
                for (int mt = 0; mt < 2; ++mt)
#pragma unroll
                    for (int nt = 0; nt < 3; ++nt)
#pragma unroll
                        for (int j = 0; j < 4; ++j) {
                            int row = tix * 64 + wm * 32 + mt * 16 + lq * 4 + j;
                            int col = wn * 48 + nt * 16 + lr;
                            float v = acc[mt][nt][j];
                            if (mat == 2) v = 1.0f / (1.0f + __expf(-v));
                            Os[(size_t)row * cC + col] = __float2bfloat16(v);
                        }
            } else {
                float* Os = (float*)O0;
#pragma unroll
                for (int mt = 0; mt < 2; ++mt)
#pragma unroll
                    for (int nt = 0; nt < 3; ++nt)
#pragma unroll
                        for (int j = 0; j < 4; ++j) {
                            int row = tix * 64 + wm * 32 + mt * 16 + lq * 4 + j;
                            int col = wn * 48 + nt * 16 + lr;
                            Os[(size_t)row * cC + col] = acc[mt][nt][j];
                        }
            }
            // ---- write next A tile into the other buffer ----
            if (i < 8) {
                char* An = &lds[0] + ((i + 1) & 1) * (64 * 384);
                if constexpr (MODE == 0) {
#pragma unroll
                    for (int j = 0; j < 3; ++j) {
                        bf16x8 pk;
                        pk[0]=(__bf16)pf[2*j].x; pk[1]=(__bf16)pf[2*j].y; pk[2]=(__bf16)pf[2*j].z; pk[3]=(__bf16)pf[2*j].w;
                        pk[4]=(__bf16)pf[2*j+1].x; pk[5]=(__bf16)pf[2*j+1].y; pk[6]=(__bf16)pf[2*j+1].z; pk[7]=(__bf16)pf[2*j+1].w;
                        *reinterpret_cast<bf16x8*>(An + swz(rj[j], kbj[j] * 16)) = pk;
                    }
                } else {
#pragma unroll
                    for (int j = 0; j < 3; ++j)
                        *reinterpret_cast<int4*>(An + swz(rj[j], kbj[j] * 16)) = pi[j];
                }
            }
            __syncthreads();
        }
    }
}

// ---------------------------------------------------------------------------
// WKV chunked scan over [m][c] bf16, 2 channels per thread (4B packed loads).
// State (p,q,o): true numerator = p*e^o, denom = q*e^o.
// ---------------------------------------------------------------------------
__global__ __launch_bounds__(192) void wkv_pass1(
    const bf* __restrict__ k, const bf* __restrict__ v,
    const float* __restrict__ sd,
    float* __restrict__ stP, float* __restrict__ stQ, float* __restrict__ stO)
{
    const int c2 = threadIdx.x % 96, sub = threadIdx.x / 96;
    const int b = blockIdx.y, ch = blockIdx.x * 2 + sub;
    const int c0 = c2 * 2;
    const float w0 = sd[c0] * Tinv, w1 = sd[c0 + 1] * Tinv;
    size_t base = ((size_t)b * cT + (size_t)ch * CH) * cC + c0;
    float p0 = 0.f, q0 = 0.f, o0 = -1e38f;
    float p1 = 0.f, q1 = 0.f, o1 = -1e38f;
    for (int s = 0; s < CH; ++s) {
        unsigned kw = *reinterpret_cast<const unsigned*>(k + base + (size_t)s * cC);
        unsigned vw = *reinterpret_cast<const unsigned*>(v + base + (size_t)s * cC);
        float kt0 = bflo(kw), kt1 = bfhi(kw);
        float vt0 = bflo(vw), vt1 = bfhi(vw);
        float no0 = fmaxf(w0 + o0, kt0);
        float A0 = __expf(w0 + o0 - no0), B0 = __expf(kt0 - no0);
        p0 = A0 * p0 + B0 * vt0; q0 = A0 * q0 + B0; o0 = no0;
        float no1 = fmaxf(w1 + o1, kt1);
        float A1 = __expf(w1 + o1 - no1), B1 = __expf(kt1 - no1);
        p1 = A1 * p1 + B1 * vt1; q1 = A1 * q1 + B1; o1 = no1;
    }
    size_t si = ((size_t)b * NS + ch) * cC + c0;
    *reinterpret_cast<float2*>(stP + si) = make_float2(p0, p1);
    *reinterpret_cast<float2*>(stQ + si) = make_float2(q0, q1);
    *reinterpret_cast<float2*>(stO + si) = make_float2(o0, o1);
}

__global__ __launch_bounds__(192) void wkv_pass2(
    const float* __restrict__ stP, const float* __restrict__ stQ,
    const float* __restrict__ stO, const float* __restrict__ sd,
    float* __restrict__ iP, float* __restrict__ iQ, float* __restrict__ iO)
{
    const int c = threadIdx.x, b = blockIdx.x;
    const float w = sd[c] * Tinv;
    const float Lw = w * (float)CH;
    float p = 0.f, q = 0.f, o = -1e38f;
    size_t si = (size_t)b * NS * cC + c;
    float sp = stP[si], sq = stQ[si], so = stO[si];
    for (int ch = 0; ch < NS; ++ch) {
        float np_ = 0.f, nq_ = 0.f, no_ = -1e38f;
        if (ch + 1 < NS) {
            size_t sj = si + (size_t)(ch + 1) * cC;
            np_ = stP[sj]; nq_ = stQ[sj]; no_ = stO[sj];
        }
        size_t sc = si + (size_t)ch * cC;
        iP[sc] = p; iQ[sc] = q; iO[sc] = o;   // exclusive prefix
        float po = o + Lw;
        float m = fmaxf(po, so);
        float e1 = __expf(po - m), e2 = __expf(so - m);
        p = e1 * p + e2 * sp;
        q = e1 * q + e2 * sq;
        o = m;
        sp = np_; sq = nq_; so = no_;
    }
}

__global__ __launch_bounds__(192) void wkv_pass3(
    const bf* __restrict__ k, const bf* __restrict__ v, const bf* __restrict__ sr,
    const float* __restrict__ sd, const float* __restrict__ sf,
    const float* __restrict__ iP, const float* __restrict__ iQ,
    const float* __restrict__ iO, bf* __restrict__ z)
{
    const int c2 = threadIdx.x % 96, sub = threadIdx.x / 96;
    const int b = blockIdx.y, ch = blockIdx.x * 2 + sub;
    const int c0 = c2 * 2;
    const float w0 = sd[c0] * Tinv, w1 = sd[c0 + 1] * Tinv;
    const float u0 = sf[c0] * Tinv, u1 = sf[c0 + 1] * Tinv;
    size_t si = ((size_t)b * NS + ch) * cC + c0;
    float2 pp = *reinterpret_cast<const float2*>(iP + si);
    float2 qq = *reinterpret_cast<const float2*>(iQ + si);
    float2 oo = *reinterpret_cast<const float2*>(iO + si);
    float p0 = pp.x, q0 = qq.x, o0 = oo.x;
    float p1 = pp.y, q1 = qq.y, o1 = oo.y;
    size_t base = ((size_t)b * cT + (size_t)ch * CH) * cC + c0;
    for (int s = 0; s < CH; ++s) {
        size_t ix = base + (size_t)s * cC;
        unsigned kw = *reinterpret_cast<const unsigned*>(k + ix);
        unsigned vw = *reinterpret_cast<const unsigned*>(v + ix);
        unsigned rw = *reinterpret_cast<const unsigned*>(sr + ix);
        float kt0 = bflo(kw), kt1 = bfhi(kw);
        float vt0 = bflo(vw), vt1 = bfhi(vw);
        float rt0 = bflo(rw), rt1 = bfhi(rw);

        float no0 = fmaxf(o0, u0 + kt0);
        float Ae0 = __expf(o0 - no0), Be0 = __expf(u0 + kt0 - no0);
        float y0 = (Ae0 * p0 + Be0 * vt0) / (Ae0 * q0 + Be0);
        float no1 = fmaxf(o1, u1 + kt1);
        float Ae1 = __expf(o1 - no1), Be1 = __expf(u1 + kt1 - no1);
        float y1 = (Ae1 * p1 + Be1 * vt1) / (Ae1 * q1 + Be1);

        bf z0 = __float2bfloat16(rt0 * y0);
        bf z1 = __float2bfloat16(rt1 * y1);
        unsigned zp = (unsigned)*reinterpret_cast<unsigned short*>(&z0)
                    | ((unsigned)*reinterpret_cast<unsigned short*>(&z1) << 16);
        *reinterpret_cast<unsigned*>(z + ix) = zp;

        float m0 = fmaxf(w0 + o0, kt0);
        float A0 = __expf(w0 + o0 - m0), B0 = __expf(kt0 - m0);
        p0 = A0 * p0 + B0 * vt0; q0 = A0 * q0 + B0; o0 = m0;
        float m1 = fmaxf(w1 + o1, kt1);
        float A1 = __expf(w1 + o1 - m1), B1 = __expf(kt1 - m1);
        p1 = A1 * p1 + B1 * vt1; q1 = A1 * q1 + B1; o1 = m1;
    }
}

extern "C" void kernel_launch(void* const* d_in, const int* in_sizes, int n_in,
                              void* d_out, int out_size, void* d_ws, size_t ws_size,
                              hipStream_t stream)
{
    const float* x  = (const float*)d_in[0];
    const float* Wk = (const float*)d_in[1];
    const float* Wv = (const float*)d_in[2];
    const float* Wr = (const float*)d_in[3];
    const float* Wo = (const float*)d_in[4];
    const float* sd = (const float*)d_in[5];
    const float* sf = (const float*)d_in[6];
    float* out = (float*)d_out;

    const size_t nEl = (size_t)cM * cC;          // 28,311,552 elements
    // d_out (f32, 113.2MB) holds k and sr (bf16, 2x56.6MB) until gemm1.
    bf* kbuf  = (bf*)d_out;
    bf* srbuf = (bf*)d_out + nEl;
    char* ws = (char*)d_ws;
    bf* vbuf = (bf*)ws;                           // 56.6MB
    bf* zbuf = (bf*)(ws + 2 * nEl);               // 56.6MB, [m][c]
    const size_t stN = (size_t)cB * NS * cC;      // 294,912 floats each
    float* stP = (float*)(ws + 4 * nEl);
    float* stQ = stP + stN;
    float* stO = stQ + stN;
    float* iP  = stO + stN;
    float* iQ  = iP + stN;
    float* iO  = iQ + stN;
    bf* wbf = (bf*)(iO + stN);                    // [Wk;Wv;Wr;Wo] bf16, 768x192

    convw_k<<<dim3(72), dim3(256), 0, stream>>>(Wk, Wv, Wr, Wo, wbf);
    gemm_k<0><<<dim3(256), dim3(512), 0, stream>>>(x, wbf, kbuf, vbuf, srbuf);
    wkv_pass1<<<dim3(NS / 2, cB), dim3(192), 0, stream>>>(kbuf, vbuf, sd, stP, stQ, stO);
    wkv_pass2<<<dim3(cB), dim3(192), 0, stream>>>(stP, stQ, stO, sd, iP, iQ, iO);
    wkv_pass3<<<dim3(NS / 2, cB), dim3(192), 0, stream>>>(
        kbuf, vbuf, srbuf, sd, sf, iP, iQ, iO, zbuf);
    gemm_k<1><<<dim3(256), dim3(512), 0, stream>>>(
        zbuf, wbf + (size_t)576 * cC, out, nullptr, nullptr);
}